// Round 7
// baseline (482.966 us; speedup 1.0000x reference)
//
#include <hip/hip_runtime.h>

#define SLOPE 0.01f
#define EPSV  1e-5f
#define BB    64
#define NN    500
#define TT    50
#define E_N   16000
#define FF    43
#define PP    500
#define HH    128
#define XSTRIDE 48

typedef const float* fp;

__device__ __forceinline__ float lrelu(float x){ return x >= 0.f ? x : SLOPE * x; }
__device__ __forceinline__ float bnap(float x, fp bnp, int c, int C){
  float g  = bnp[c], b_ = bnp[C + c];
  float m  = bnp[2*C + c], v = bnp[3*C + c];
  float s = g * rsqrtf(v + EPSV);
  return x * s + (b_ - m * s);
}

// ============ CSR/weight prep chain (parallelized; was 1-block serial) ============
__global__ __launch_bounds__(1024) void k_prep(
    fp sc2w, fp mc2w, fp gwroot, fp gwrel,
    float* __restrict__ wT_s2, float* __restrict__ wT_m2, float* __restrict__ wTg,
    int* __restrict__ cnt, int* __restrict__ ideg)
{
  int tid = threadIdx.x;
  for (int i = tid; i < 2880; i += 1024) wT_s2[(i%144)*20 + i/144] = sc2w[i];
  for (int i = tid; i < 1800; i += 1024) wT_m2[(i%90)*20 + i/90]  = mc2w[i];
  for (int i = tid; i < 9245; i += 1024){
    int f5 = i/43, gg = i%43;
    wTg[i] = (f5 < 43) ? gwroot[f5*43+gg] : gwrel[(f5-43)*43+gg];
  }
  for (int i = tid; i < 43;   i += 1024) wTg[9245+i] = 0.f;   // pad row (c=43 lane)
  for (int i = tid; i < 512;  i += 1024) cnt[i] = 0;
  for (int i = tid; i < 2000; i += 1024) ideg[i] = 0;
}

__global__ __launch_bounds__(256) void k_count(
    const int* __restrict__ ei, const int* __restrict__ et,
    int* __restrict__ cnt, int* __restrict__ ideg)
{
  int i = blockIdx.x*256 + threadIdx.x;
  if (i < E_N){
    int d = ei[E_N+i], r = et[i];
    atomicAdd(&cnt[d], 1);
    atomicAdd(&ideg[r*NN+d], 1);
  }
}

__global__ __launch_bounds__(512) void k_scan(
    const int* __restrict__ cnt, const int* __restrict__ ideg,
    int* __restrict__ offs, int* __restrict__ cursor, float* __restrict__ inv_deg)
{
  __shared__ int sc[512];
  int tid = threadIdx.x;
  sc[tid] = cnt[tid];
  __syncthreads();
  for (int off = 1; off < 512; off <<= 1){
    int v = (tid >= off) ? sc[tid-off] : 0;
    __syncthreads();
    sc[tid] += v;
    __syncthreads();
  }
  if (tid <= NN) offs[tid]  = (tid == 0) ? 0 : sc[tid-1];
  if (tid <  NN) cursor[tid]= (tid == 0) ? 0 : sc[tid-1];
  for (int i = tid; i < 2000; i += 512)
    inv_deg[i] = 1.f / fmaxf((float)ideg[i], 1.f);
}

__global__ __launch_bounds__(256) void k_fill(
    const int* __restrict__ ei, const int* __restrict__ et,
    int* __restrict__ cursor, int* __restrict__ e_src, int* __restrict__ e_typ)
{
  int i = blockIdx.x*256 + threadIdx.x;
  if (i < E_N){
    int s = ei[i], d = ei[E_N+i], r = et[i];
    int pos = atomicAdd(&cursor[d], 1);
    e_src[pos] = s; e_typ[pos] = r;
  }
}

// ============ Kernel A: temporal features, NODE-MAJOR (lane = node) ============
// 500 blocks x 64 lanes; each lane owns one (b,n). Weights are wave-uniform
// (scalar loads); conv2 fused into conv1 output loop (s1/m1 never materialized).
__global__ __launch_bounds__(64) void k_tempo_nm(
    fp obs, fp sc1w, fp sc1b, fp sbn1, fp sc2b, fp sbn2,
    fp mc1w, fp mc1b, fp mbn1, fp mc2b, fp mbn2,
    const float* __restrict__ wT_s2, const float* __restrict__ wT_m2,
    float* __restrict__ xbuf)
{
  __shared__ float ol[64][151];    // 151 odd -> conflict-free per-lane rows
  int lane = threadIdx.x;
  int g = blockIdx.x*64 + lane;    // global node id = b*500+n
  int b = g / NN, n = g % NN;
  const float* orow = obs + (size_t)b*75000 + (size_t)n*50;  // +c*25000 + t

  for (int c = 0; c < 3; c++){
    #pragma unroll 10
    for (int t = 0; t < 50; t++)
      ol[lane][c*50 + t] = orow[c*25000 + t];
  }
  // single wave: compiler inserts lgkmcnt before dependent ds_reads

  float acc[20];
  // ---- s-branch: conv1(k=3)+bn+lrelu fused into conv2(k=48) accumulation ----
  #pragma unroll
  for (int o = 0; o < 20; o++) acc[o] = sc2b[o];
  for (int t = 0; t < 48; t++){
    float sv[3];
    #pragma unroll
    for (int co = 0; co < 3; co++) sv[co] = sc1b[co];
    #pragma unroll
    for (int ci = 0; ci < 3; ci++){
      #pragma unroll
      for (int k = 0; k < 3; k++){
        float v = ol[lane][ci*50 + t + k];
        #pragma unroll
        for (int co = 0; co < 3; co++)
          sv[co] += v * sc1w[co*9 + ci*3 + k];
      }
    }
    #pragma unroll
    for (int co = 0; co < 3; co++){
      float z = lrelu(bnap(sv[co], sbn1, co, 3));
      const float* wp = wT_s2 + (co*48 + t)*20;   // uniform -> s_load
      #pragma unroll
      for (int o = 0; o < 20; o++) acc[o] += z * wp[o];
    }
  }
  #pragma unroll
  for (int o = 0; o < 20; o++)
    xbuf[(size_t)g*XSTRIDE + o] = lrelu(bnap(acc[o], sbn2, o, 20));

  // ---- m-branch: conv1(k=21)+bn+lrelu fused into conv2(k=30) ----
  #pragma unroll
  for (int o = 0; o < 20; o++) acc[o] = mc2b[o];
  for (int t = 0; t < 30; t++){
    float mv[3];
    #pragma unroll
    for (int co = 0; co < 3; co++) mv[co] = mc1b[co];
    #pragma unroll
    for (int ci = 0; ci < 3; ci++){
      #pragma unroll
      for (int k = 0; k < 21; k++){
        float v = ol[lane][ci*50 + t + k];
        #pragma unroll
        for (int co = 0; co < 3; co++)
          mv[co] += v * mc1w[co*63 + ci*21 + k];
      }
    }
    #pragma unroll
    for (int co = 0; co < 3; co++){
      float z = lrelu(bnap(mv[co], mbn1, co, 3));
      const float* wp = wT_m2 + (co*30 + t)*20;
      #pragma unroll
      for (int o = 0; o < 20; o++) acc[o] += z * wp[o];
    }
  }
  #pragma unroll
  for (int o = 0; o < 20; o++)
    xbuf[(size_t)g*XSTRIDE + 20 + o] = lrelu(bnap(acc[o], mbn2, o, 20));

  // ---- l-branch: max over T ----
  #pragma unroll
  for (int c = 0; c < 3; c++){
    float mx = ol[lane][c*50];
    #pragma unroll 7
    for (int t = 1; t < 50; t++) mx = fmaxf(mx, ol[lane][c*50 + t]);
    xbuf[(size_t)g*XSTRIDE + 40 + c] = lrelu(mx);
  }
}

// ============ Kernel B: graph layer, fused agg (lane=feature) + transform
// (lane=node, scalar weights). 500 blocks x 256 threads (4 waves, 64 nodes). ====
__global__ __launch_bounds__(256) void k_graph_nm(
    const float* __restrict__ xbuf, const float* __restrict__ wTg,
    fp gb, fp gbnp, const float* __restrict__ inv_deg,
    const int* __restrict__ offs, const int* __restrict__ e_src,
    const int* __restrict__ e_typ, float* __restrict__ gbuf)
{
  __shared__ float xin[64][219];   // 219 odd -> conflict-free
  int tid = threadIdx.x;
  int w = tid >> 6, lane = tid & 63;

  // phase 1: each wave aggregates 16 nodes (lane = feature)
  for (int q = 0; q < 16; q++){
    int nl = w*16 + q;
    int g = __builtin_amdgcn_readfirstlane(blockIdx.x*64 + nl);
    int b = g / NN, n = g % NN;
    const float* xb = xbuf + (size_t)b*NN*XSTRIDE;
    if (lane < FF) xin[nl][lane] = xb[n*XSTRIDE + lane];
    float a0=0.f, a1=0.f, a2=0.f, a3=0.f;
    int beg = offs[n], end = offs[n+1];
    for (int i = beg; i < end; i++){
      int s = e_src[i], r = e_typ[i];
      float v = (lane < FF) ? xb[s*XSTRIDE + lane] : 0.f;
      a0 += (r == 0) ? v : 0.f;
      a1 += (r == 1) ? v : 0.f;
      a2 += (r == 2) ? v : 0.f;
      a3 += (r == 3) ? v : 0.f;
    }
    if (lane < FF){
      xin[nl][ 43 + lane] = a0 * inv_deg[0*NN + n];
      xin[nl][ 86 + lane] = a1 * inv_deg[1*NN + n];
      xin[nl][129 + lane] = a2 * inv_deg[2*NN + n];
      xin[nl][172 + lane] = a3 * inv_deg[3*NN + n];
    }
  }
  __syncthreads();

  // phase 2: lane = node; wave w computes output channels [w*11, w*11+11)
  int c0 = __builtin_amdgcn_readfirstlane(w*11);
  int g = blockIdx.x*64 + lane;
  float acc[11];
  #pragma unroll
  for (int j = 0; j < 11; j++) acc[j] = (c0 + j < FF) ? gb[c0+j] : 0.f;
  for (int f = 0; f < 215; f++){
    float v = xin[lane][f];
    const float* wp = wTg + f*43 + c0;   // uniform -> s_load (padded row f*43+43 safe)
    #pragma unroll
    for (int j = 0; j < 11; j++) acc[j] += v * wp[j];
  }
  #pragma unroll
  for (int j = 0; j < 11; j++){
    int c = c0 + j;
    if (c < FF)
      gbuf[(size_t)g*XSTRIDE + c] = lrelu(bnap(acc[j], gbnp, c, FF));
  }
}

// ============ Kernel C: head (unchanged from r6) ============
__global__ __launch_bounds__(512) void k_head_r6(
    const float* __restrict__ xbuf, const float* __restrict__ gbuf,
    fp action, const int* __restrict__ nts,
    fp acw, fp acb, fp aw1, fp ab1, fp aw2, fp ab2, fp aw3, fp ab3,
    float* __restrict__ out)
{
  int b = blockIdx.x;
  int tid = threadIdx.x;
  __shared__ float o[PP+1];
  __shared__ float h1[HH];
  __shared__ float h2[HH];
  __shared__ float red[512];

  if (tid < PP){
    int np = nts[tid];
    const float* xr = xbuf + (size_t)(b*NN + np)*XSTRIDE;
    const float* gr = gbuf + (size_t)(b*NN + np)*XSTRIDE;
    float acc = acb[0] + action[b*(PP+1) + 1 + tid] * acw[0];
    for (int c = 0; c < FF; c++) acc += xr[c] * acw[1 + c];
    for (int c = 0; c < FF; c++) acc += gr[c] * acw[1 + FF + c];
    o[1 + tid] = acc;
  }
  if (tid == 511) o[0] = 0.f;
  __syncthreads();

  if (tid < HH){
    float acc = ab1[tid];
    for (int k = 0; k <= PP; k++) acc += o[k] * aw1[k*HH + tid];
    h1[tid] = fmaxf(acc, 0.f);
  }
  __syncthreads();
  if (tid < HH){
    float acc = ab2[tid];
    for (int k = 0; k < HH; k++) acc += h1[k] * aw2[k*HH + tid];
    h2[tid] = fmaxf(acc, 0.f);
  }
  __syncthreads();

  float val = -1e30f;
  if (tid <= PP){
    float acc = ab3[tid];
    for (int k = 0; k < HH; k++) acc += h2[k] * aw3[k*(PP+1) + tid];
    val = acc;
  }
  red[tid] = val;
  __syncthreads();
  for (int s = 256; s > 0; s >>= 1){
    if (tid < s) red[tid] = fmaxf(red[tid], red[tid + s]);
    __syncthreads();
  }
  float mx = red[0];
  __syncthreads();
  float e = (tid <= PP) ? expf(val - mx) : 0.f;
  red[tid] = e;
  __syncthreads();
  for (int s = 256; s > 0; s >>= 1){
    if (tid < s) red[tid] += red[tid + s];
    __syncthreads();
  }
  float sum = red[0];
  if (tid <= PP) out[b*(PP+1) + tid] = e / sum;
}

extern "C" void kernel_launch(void* const* d_in, const int* in_sizes, int n_in,
                              void* d_out, int out_size, void* d_ws, size_t ws_size,
                              hipStream_t stream)
{
  fp obs    = (fp)d_in[0];
  fp action = (fp)d_in[1];
  const int* ei  = (const int*)d_in[2];
  const int* et  = (const int*)d_in[3];
  const int* nts = (const int*)d_in[4];
  fp sc1w=(fp)d_in[5],  sc1b=(fp)d_in[6],  sbn1=(fp)d_in[7];
  fp sc2w=(fp)d_in[8],  sc2b=(fp)d_in[9],  sbn2=(fp)d_in[10];
  fp mc1w=(fp)d_in[11], mc1b=(fp)d_in[12], mbn1=(fp)d_in[13];
  fp mc2w=(fp)d_in[14], mc2b=(fp)d_in[15], mbn2=(fp)d_in[16];
  fp gwroot=(fp)d_in[17], gwrel=(fp)d_in[18], gb=(fp)d_in[19], gbnp=(fp)d_in[20];
  fp acw=(fp)d_in[21], acb=(fp)d_in[22];
  fp aw1=(fp)d_in[23], ab1=(fp)d_in[24];
  fp aw2=(fp)d_in[25], ab2=(fp)d_in[26];
  fp aw3=(fp)d_in[27], ab3=(fp)d_in[28];

  float* xbuf   = (float*)d_ws;              // 32000*48
  float* gbuf   = xbuf + 1536000;            // 32000*48
  float* wT_s2  = gbuf + 1536000;            // 2880
  float* wT_m2  = wT_s2 + 2880;              // 1800
  float* wTg    = wT_m2 + 1800;              // 9245 + 43 pad
  float* invdeg = wTg + 9288;                // 2000
  int*   ip     = (int*)(invdeg + 2000);
  int* cnt    = ip;            // 512
  int* ideg   = ip + 512;      // 2000
  int* offs   = ip + 2512;     // 501
  int* cursor = ip + 3013;     // 500
  int* e_src  = ip + 3513;     // 16000
  int* e_typ  = ip + 19513;    // 16000

  float* out = (float*)d_out;

  hipLaunchKernelGGL(k_prep, dim3(1), dim3(1024), 0, stream,
    sc2w, mc2w, gwroot, gwrel, wT_s2, wT_m2, wTg, cnt, ideg);
  hipLaunchKernelGGL(k_count, dim3(63), dim3(256), 0, stream,
    ei, et, cnt, ideg);
  hipLaunchKernelGGL(k_scan, dim3(1), dim3(512), 0, stream,
    cnt, ideg, offs, cursor, invdeg);
  hipLaunchKernelGGL(k_fill, dim3(63), dim3(256), 0, stream,
    ei, et, cursor, e_src, e_typ);
  hipLaunchKernelGGL(k_tempo_nm, dim3(500), dim3(64), 0, stream,
    obs, sc1w, sc1b, sbn1, sc2b, sbn2,
    mc1w, mc1b, mbn1, mc2b, mbn2, wT_s2, wT_m2, xbuf);
  hipLaunchKernelGGL(k_graph_nm, dim3(500), dim3(256), 0, stream,
    xbuf, wTg, gb, gbnp, invdeg, offs, e_src, e_typ, gbuf);
  hipLaunchKernelGGL(k_head_r6, dim3(BB), dim3(512), 0, stream,
    xbuf, gbuf, action, nts, acw, acb, aw1, ab1, aw2, ab2, aw3, ab3, out);
}

// Round 8
// 391.995 us; speedup vs baseline: 1.2321x; 1.2321x over previous
//
#include <hip/hip_runtime.h>

#define SLOPE 0.01f
#define EPSV  1e-5f
#define BB    64
#define NN    500
#define TT    50
#define E_N   16000
#define FF    43
#define PP    500
#define HH    128
#define XSTRIDE 48

typedef const float* fp;

__device__ __forceinline__ float lrelu(float x){ return x >= 0.f ? x : SLOPE * x; }
__device__ __forceinline__ float bnap(float x, fp bnp, int c, int C){
  float g  = bnp[c], b_ = bnp[C + c];
  float m  = bnp[2*C + c], v = bnp[3*C + c];
  float s = g * rsqrtf(v + EPSV);
  return x * s + (b_ - m * s);
}

// ============ prep: weight transposes + zeroing (8 blocks) ============
__global__ __launch_bounds__(1024) void k_prep8(
    fp sc2w, fp mc2w, fp gwroot, fp gwrel,
    float* __restrict__ wT_s2, float* __restrict__ wT_m2, float* __restrict__ wTg,
    int* __restrict__ cnt, int* __restrict__ ideg)
{
  int tid = threadIdx.x, blk = blockIdx.x;
  if (blk == 0){
    for (int i = tid; i < 2880; i += 1024){ int o = i/144, x = i%144; wT_s2[x*20+o] = sc2w[i]; }
  } else if (blk == 1){
    for (int i = tid; i < 1800; i += 1024){ int o = i/90,  x = i%90;  wT_m2[x*20+o] = mc2w[i]; }
  } else if (blk < 6){
    for (int i = (blk-2)*1024 + tid; i < 9245; i += 4096){
      int f5 = i/43, g = i%43;
      wTg[i] = (f5 < 43) ? gwroot[f5*43+g] : gwrel[(f5-43)*43+g];
    }
  } else if (blk == 6){
    for (int i = tid; i < 512;  i += 1024) cnt[i] = 0;
    for (int i = tid; i < 2048; i += 1024) ideg[i] = 0;
  } else {
    for (int i = 9245 + tid; i < 9312; i += 1024) wTg[i] = 0.f;
  }
}

__global__ __launch_bounds__(256) void k_count8(
    const int* __restrict__ ei, const int* __restrict__ et,
    int* __restrict__ cnt, int* __restrict__ ideg)
{
  int i = blockIdx.x*256 + threadIdx.x;
  if (i < E_N){
    int d = ei[E_N+i], r = et[i];
    atomicAdd(&cnt[d], 1);
    atomicAdd(&ideg[r*NN+d], 1);
  }
}

// offsets for (dst, rel)-sorted CSR; begr[d*4+r], begr[2000]=E_N sentinel
__global__ __launch_bounds__(512) void k_scan8(
    const int* __restrict__ cnt, const int* __restrict__ ideg,
    int* __restrict__ begr, int* __restrict__ cursor4, float* __restrict__ inv_deg)
{
  __shared__ int sc[512];
  int tid = threadIdx.x;
  sc[tid] = cnt[tid];
  __syncthreads();
  for (int off = 1; off < 512; off <<= 1){
    int v = (tid >= off) ? sc[tid-off] : 0;
    __syncthreads();
    sc[tid] += v;
    __syncthreads();
  }
  if (tid < NN){
    int o  = tid ? sc[tid-1] : 0;
    int c1 = o  + ideg[tid];
    int c2 = c1 + ideg[NN + tid];
    int c3 = c2 + ideg[2*NN + tid];
    begr[tid*4+0] = o;  begr[tid*4+1] = c1;
    begr[tid*4+2] = c2; begr[tid*4+3] = c3;
    cursor4[tid*4+0] = o;  cursor4[tid*4+1] = c1;
    cursor4[tid*4+2] = c2; cursor4[tid*4+3] = c3;
    #pragma unroll
    for (int r = 0; r < 4; r++)
      inv_deg[r*NN+tid] = 1.f / fmaxf((float)ideg[r*NN+tid], 1.f);
  }
  if (tid == 0) begr[2000] = E_N;
}

__global__ __launch_bounds__(256) void k_fill8(
    const int* __restrict__ ei, const int* __restrict__ et,
    int* __restrict__ cursor4, int* __restrict__ e_s)
{
  int i = blockIdx.x*256 + threadIdx.x;
  if (i < E_N){
    int s = ei[i], d = ei[E_N+i], r = et[i];
    int pos = atomicAdd(&cursor4[d*4+r], 1);
    e_s[pos] = s;
  }
}

// ============ temporal: uniform-b blocks, coalesced obs stage ============
// grid 512: blk/8 = b, (blk%8)*64 = n0; lane = node
__global__ __launch_bounds__(64) void k_tempo8(
    fp obs, fp sc1w, fp sc1b, fp sbn1, fp sc2b, fp sbn2,
    fp mc1w, fp mc1b, fp mbn1, fp mc2b, fp mbn2,
    const float* __restrict__ wT_s2, const float* __restrict__ wT_m2,
    float* __restrict__ xbuf)
{
  __shared__ float ol[64][151];
  int lane = threadIdx.x;
  int b  = blockIdx.x >> 3;
  int n0 = (blockIdx.x & 7) << 6;
  int span = (NN - n0 < 64) ? (NN - n0) : 64;   // 52 for last tile
  int n = n0 + lane;

  for (int c = 0; c < 3; c++){
    const float* base = obs + ((size_t)(b*3 + c)*NN + n0)*TT;
    for (int j = lane; j < span*50; j += 64)
      ol[j/50][c*50 + j%50] = base[j];
  }
  __syncthreads();
  if (n < NN){
    size_t gx = (size_t)(b*NN + n)*XSTRIDE;
    float acc[20];
    // s-branch
    #pragma unroll
    for (int o = 0; o < 20; o++) acc[o] = sc2b[o];
    for (int t = 0; t < 48; t++){
      float sv[3];
      #pragma unroll
      for (int co = 0; co < 3; co++) sv[co] = sc1b[co];
      #pragma unroll
      for (int ci = 0; ci < 3; ci++)
        #pragma unroll
        for (int k = 0; k < 3; k++){
          float v = ol[lane][ci*50 + t + k];
          #pragma unroll
          for (int co = 0; co < 3; co++) sv[co] += v * sc1w[co*9 + ci*3 + k];
        }
      #pragma unroll
      for (int co = 0; co < 3; co++){
        float z = lrelu(bnap(sv[co], sbn1, co, 3));
        const float* wp = wT_s2 + (co*48 + t)*20;
        #pragma unroll
        for (int o = 0; o < 20; o++) acc[o] += z * wp[o];
      }
    }
    #pragma unroll
    for (int o = 0; o < 20; o++) xbuf[gx + o] = lrelu(bnap(acc[o], sbn2, o, 20));
    // m-branch
    #pragma unroll
    for (int o = 0; o < 20; o++) acc[o] = mc2b[o];
    for (int t = 0; t < 30; t++){
      float mv[3];
      #pragma unroll
      for (int co = 0; co < 3; co++) mv[co] = mc1b[co];
      #pragma unroll
      for (int ci = 0; ci < 3; ci++)
        #pragma unroll
        for (int k = 0; k < 21; k++){
          float v = ol[lane][ci*50 + t + k];
          #pragma unroll
          for (int co = 0; co < 3; co++) mv[co] += v * mc1w[co*63 + ci*21 + k];
        }
      #pragma unroll
      for (int co = 0; co < 3; co++){
        float z = lrelu(bnap(mv[co], mbn1, co, 3));
        const float* wp = wT_m2 + (co*30 + t)*20;
        #pragma unroll
        for (int o = 0; o < 20; o++) acc[o] += z * wp[o];
      }
    }
    #pragma unroll
    for (int o = 0; o < 20; o++) xbuf[gx + 20 + o] = lrelu(bnap(acc[o], mbn2, o, 20));
    // l-branch
    #pragma unroll
    for (int c = 0; c < 3; c++){
      float mx = ol[lane][c*50];
      #pragma unroll 7
      for (int t = 1; t < 50; t++) mx = fmaxf(mx, ol[lane][c*50 + t]);
      xbuf[gx + 40 + c] = lrelu(mx);
    }
  }
}

// ============ graph: 1024-thread blocks, wave-per-node agg + scalar-weight
// transform. 500 blocks; LDS 56 KB -> 2 blocks/CU = 100% occupancy. ============
__global__ __launch_bounds__(1024) void k_graph8(
    const float* __restrict__ xbuf, const float* __restrict__ wTg,
    fp gb, fp gbnp, const float* __restrict__ inv_deg,
    const int* __restrict__ begr, const int* __restrict__ e_s,
    float* __restrict__ gbuf)
{
  __shared__ float xin[64][219];
  int tid = threadIdx.x;
  int w = tid >> 6, lane = tid & 63;
  int g0 = blockIdx.x * 64;

  // phase 1: each of 16 waves aggregates 4 nodes; relation-sorted edge runs
  for (int q = 0; q < 4; q++){
    int nl = (w << 2) + q;
    int g = __builtin_amdgcn_readfirstlane(g0 + nl);
    int b = g / NN;
    int n = g - b * NN;
    int gb0 = b * NN;
    float xv = (lane < FF) ? xbuf[(size_t)g*XSTRIDE + lane] : 0.f;
    float ar[4];
    #pragma unroll
    for (int r = 0; r < 4; r++){
      int beg = __builtin_amdgcn_readfirstlane(begr[n*4 + r]);
      int end = __builtin_amdgcn_readfirstlane(begr[n*4 + r + 1]);
      float a = 0.f;
      for (int i = beg; i < end; i++){
        int s = e_s[i];                       // scalar load
        a += (lane < FF) ? xbuf[(size_t)(gb0 + s)*XSTRIDE + lane] : 0.f;
      }
      ar[r] = a * inv_deg[r*NN + n];
    }
    if (lane < FF){
      xin[nl][lane]       = xv;
      xin[nl][ 43 + lane] = ar[0];
      xin[nl][ 86 + lane] = ar[1];
      xin[nl][129 + lane] = ar[2];
      xin[nl][172 + lane] = ar[3];
    }
  }
  __syncthreads();

  // phase 2: lane = node; wave w computes channels [w*3, w*3+3)
  int c0 = __builtin_amdgcn_readfirstlane(w * 3);
  int g = g0 + lane;
  float acc[3];
  #pragma unroll
  for (int j = 0; j < 3; j++) acc[j] = (c0 + j < FF) ? gb[c0+j] : 0.f;
  for (int f = 0; f < 215; f++){
    float v = xin[lane][f];
    const float* wp = wTg + f*43 + c0;        // uniform -> s_load (padded)
    #pragma unroll
    for (int j = 0; j < 3; j++) acc[j] += v * wp[j];
  }
  #pragma unroll
  for (int j = 0; j < 3; j++){
    int c = c0 + j;
    if (c < FF)
      gbuf[(size_t)g*XSTRIDE + c] = lrelu(bnap(acc[j], gbnp, c, FF));
  }
}

// ============ head: tiled coalesced gather + chunked fc1 ============
__global__ __launch_bounds__(512) void k_head8(
    const float* __restrict__ xbuf, const float* __restrict__ gbuf,
    fp action, const int* __restrict__ nts,
    fp acw, fp acb, fp aw1, fp ab1, fp aw2, fp ab2, fp aw3, fp ab3,
    float* __restrict__ out)
{
  int b = blockIdx.x;
  int tid = threadIdx.x;
  __shared__ float feats[64][87];
  __shared__ float o[PP+1];
  __shared__ float h1[HH];
  __shared__ float h2[HH];
  __shared__ float part[4][HH];
  __shared__ float red[512];

  for (int tile = 0; tile < 8; tile++){
    int p0 = tile * 64;
    __syncthreads();
    for (int j = tid; j < 64*86; j += 512){
      int q = j / 86, c = j % 86;
      int p = p0 + q;
      if (p < PP){
        int np = nts[p];
        size_t row = (size_t)(b*NN + np)*XSTRIDE;
        feats[q][c] = (c < FF) ? xbuf[row + c] : gbuf[row + (c - FF)];
      }
    }
    __syncthreads();
    if (tid < 64){
      int p = p0 + tid;
      if (p < PP){
        float acc = acb[0] + action[b*(PP+1) + 1 + p] * acw[0];
        for (int c = 0; c < 86; c++) acc += feats[tid][c] * acw[1 + c];
        o[1 + p] = acc;
      }
    }
  }
  if (tid == 511) o[0] = 0.f;
  __syncthreads();

  // fc1: 4 chunks x 128 threads
  {
    int chunk = tid >> 7, h = tid & 127;
    int k0 = chunk * 125;
    int k1 = (chunk == 3) ? (PP+1) : k0 + 125;
    float acc = 0.f;
    for (int k = k0; k < k1; k++) acc += o[k] * aw1[k*HH + h];
    part[chunk][h] = acc;
  }
  __syncthreads();
  if (tid < HH)
    h1[tid] = fmaxf(ab1[tid] + part[0][tid] + part[1][tid] + part[2][tid] + part[3][tid], 0.f);
  __syncthreads();
  if (tid < HH){
    float acc = ab2[tid];
    for (int k = 0; k < HH; k++) acc += h1[k] * aw2[k*HH + tid];
    h2[tid] = fmaxf(acc, 0.f);
  }
  __syncthreads();

  float val = -1e30f;
  if (tid <= PP){
    float acc = ab3[tid];
    for (int k = 0; k < HH; k++) acc += h2[k] * aw3[k*(PP+1) + tid];
    val = acc;
  }
  red[tid] = val;
  __syncthreads();
  for (int s = 256; s > 0; s >>= 1){
    if (tid < s) red[tid] = fmaxf(red[tid], red[tid + s]);
    __syncthreads();
  }
  float mx = red[0];
  __syncthreads();
  float e = (tid <= PP) ? expf(val - mx) : 0.f;
  red[tid] = e;
  __syncthreads();
  for (int s = 256; s > 0; s >>= 1){
    if (tid < s) red[tid] += red[tid + s];
    __syncthreads();
  }
  float sum = red[0];
  if (tid <= PP) out[b*(PP+1) + tid] = e / sum;
}

extern "C" void kernel_launch(void* const* d_in, const int* in_sizes, int n_in,
                              void* d_out, int out_size, void* d_ws, size_t ws_size,
                              hipStream_t stream)
{
  fp obs    = (fp)d_in[0];
  fp action = (fp)d_in[1];
  const int* ei  = (const int*)d_in[2];
  const int* et  = (const int*)d_in[3];
  const int* nts = (const int*)d_in[4];
  fp sc1w=(fp)d_in[5],  sc1b=(fp)d_in[6],  sbn1=(fp)d_in[7];
  fp sc2w=(fp)d_in[8],  sc2b=(fp)d_in[9],  sbn2=(fp)d_in[10];
  fp mc1w=(fp)d_in[11], mc1b=(fp)d_in[12], mbn1=(fp)d_in[13];
  fp mc2w=(fp)d_in[14], mc2b=(fp)d_in[15], mbn2=(fp)d_in[16];
  fp gwroot=(fp)d_in[17], gwrel=(fp)d_in[18], gb=(fp)d_in[19], gbnp=(fp)d_in[20];
  fp acw=(fp)d_in[21], acb=(fp)d_in[22];
  fp aw1=(fp)d_in[23], ab1=(fp)d_in[24];
  fp aw2=(fp)d_in[25], ab2=(fp)d_in[26];
  fp aw3=(fp)d_in[27], ab3=(fp)d_in[28];

  float* xbuf   = (float*)d_ws;              // 1,536,000
  float* gbuf   = xbuf + 1536000;            // 1,536,000
  float* wT_s2  = gbuf + 1536000;            // 2880
  float* wT_m2  = wT_s2 + 2880;              // 1800
  float* wTg    = wT_m2 + 1800;              // 9312 (incl. pad)
  float* invdeg = wTg + 9312;                // 2000
  int*   ip     = (int*)(invdeg + 2000);
  int* cnt     = ip;            // 512
  int* ideg    = ip + 512;      // 2048
  int* begr    = ip + 2560;     // 2001
  int* cursor4 = ip + 4561;     // 2000
  int* e_s     = ip + 6561;     // 16000

  float* out = (float*)d_out;

  hipLaunchKernelGGL(k_prep8, dim3(8), dim3(1024), 0, stream,
    sc2w, mc2w, gwroot, gwrel, wT_s2, wT_m2, wTg, cnt, ideg);
  hipLaunchKernelGGL(k_count8, dim3(63), dim3(256), 0, stream,
    ei, et, cnt, ideg);
  hipLaunchKernelGGL(k_scan8, dim3(1), dim3(512), 0, stream,
    cnt, ideg, begr, cursor4, invdeg);
  hipLaunchKernelGGL(k_fill8, dim3(63), dim3(256), 0, stream,
    ei, et, cursor4, e_s);
  hipLaunchKernelGGL(k_tempo8, dim3(512), dim3(64), 0, stream,
    obs, sc1w, sc1b, sbn1, sc2b, sbn2,
    mc1w, mc1b, mbn1, mc2b, mbn2, wT_s2, wT_m2, xbuf);
  hipLaunchKernelGGL(k_graph8, dim3(500), dim3(1024), 0, stream,
    xbuf, wTg, gb, gbnp, invdeg, begr, e_s, gbuf);
  hipLaunchKernelGGL(k_head8, dim3(BB), dim3(512), 0, stream,
    xbuf, gbuf, action, nts, acw, acb, aw1, ab1, aw2, ab2, aw3, ab3, out);
}

// Round 9
// 325.550 us; speedup vs baseline: 1.4835x; 1.2041x over previous
//
#include <hip/hip_runtime.h>

#define SLOPE 0.01f
#define EPSV  1e-5f
#define BB    64
#define NN    500
#define TT    50
#define E_N   16000
#define FF    43
#define PP    500
#define HH    128
#define XSTRIDE 48

typedef const float* fp;

__device__ __forceinline__ float lrelu(float x){ return x >= 0.f ? x : SLOPE * x; }
__device__ __forceinline__ float bnap(float x, fp bnp, int c, int C){
  float g  = bnp[c], b_ = bnp[C + c];
  float m  = bnp[2*C + c], v = bnp[3*C + c];
  float s = g * rsqrtf(v + EPSV);
  return x * s + (b_ - m * s);
}

// ============ prep: weight transposes + zeroing (8 blocks) ============
__global__ __launch_bounds__(1024) void k_prep8(
    fp sc2w, fp mc2w, fp gwroot, fp gwrel,
    float* __restrict__ wT_s2, float* __restrict__ wT_m2, float* __restrict__ wTg,
    int* __restrict__ cnt, int* __restrict__ ideg)
{
  int tid = threadIdx.x, blk = blockIdx.x;
  if (blk == 0){
    for (int i = tid; i < 2880; i += 1024){ int o = i/144, x = i%144; wT_s2[x*20+o] = sc2w[i]; }
  } else if (blk == 1){
    for (int i = tid; i < 1800; i += 1024){ int o = i/90,  x = i%90;  wT_m2[x*20+o] = mc2w[i]; }
  } else if (blk < 6){
    for (int i = (blk-2)*1024 + tid; i < 9245; i += 4096){
      int f5 = i/43, g = i%43;
      wTg[i] = (f5 < 43) ? gwroot[f5*43+g] : gwrel[(f5-43)*43+g];
    }
  } else if (blk == 6){
    for (int i = tid; i < 512;  i += 1024) cnt[i] = 0;
    for (int i = tid; i < 2048; i += 1024) ideg[i] = 0;
  } else {
    for (int i = 9245 + tid; i < 9312; i += 1024) wTg[i] = 0.f;
  }
}

__global__ __launch_bounds__(256) void k_count8(
    const int* __restrict__ ei, const int* __restrict__ et,
    int* __restrict__ cnt, int* __restrict__ ideg)
{
  int i = blockIdx.x*256 + threadIdx.x;
  if (i < E_N){
    int d = ei[E_N+i], r = et[i];
    atomicAdd(&cnt[d], 1);
    atomicAdd(&ideg[r*NN+d], 1);
  }
}

__global__ __launch_bounds__(512) void k_scan8(
    const int* __restrict__ cnt, const int* __restrict__ ideg,
    int* __restrict__ begr, int* __restrict__ cursor4, float* __restrict__ inv_deg)
{
  __shared__ int sc[512];
  int tid = threadIdx.x;
  sc[tid] = cnt[tid];
  __syncthreads();
  for (int off = 1; off < 512; off <<= 1){
    int v = (tid >= off) ? sc[tid-off] : 0;
    __syncthreads();
    sc[tid] += v;
    __syncthreads();
  }
  if (tid < NN){
    int o  = tid ? sc[tid-1] : 0;
    int c1 = o  + ideg[tid];
    int c2 = c1 + ideg[NN + tid];
    int c3 = c2 + ideg[2*NN + tid];
    begr[tid*4+0] = o;  begr[tid*4+1] = c1;
    begr[tid*4+2] = c2; begr[tid*4+3] = c3;
    cursor4[tid*4+0] = o;  cursor4[tid*4+1] = c1;
    cursor4[tid*4+2] = c2; cursor4[tid*4+3] = c3;
    #pragma unroll
    for (int r = 0; r < 4; r++)
      inv_deg[r*NN+tid] = 1.f / fmaxf((float)ideg[r*NN+tid], 1.f);
  }
  if (tid == 0) begr[2000] = E_N;
}

__global__ __launch_bounds__(256) void k_fill8(
    const int* __restrict__ ei, const int* __restrict__ et,
    int* __restrict__ cursor4, int* __restrict__ e_s)
{
  int i = blockIdx.x*256 + threadIdx.x;
  if (i < E_N){
    int s = ei[i], d = ei[E_N+i], r = et[i];
    int pos = atomicAdd(&cursor4[d*4+r], 1);
    e_s[pos] = s;
  }
}

// ============ temporal (unchanged from r8) ============
__global__ __launch_bounds__(64) void k_tempo8(
    fp obs, fp sc1w, fp sc1b, fp sbn1, fp sc2b, fp sbn2,
    fp mc1w, fp mc1b, fp mbn1, fp mc2b, fp mbn2,
    const float* __restrict__ wT_s2, const float* __restrict__ wT_m2,
    float* __restrict__ xbuf)
{
  __shared__ float ol[64][151];
  int lane = threadIdx.x;
  int b  = blockIdx.x >> 3;
  int n0 = (blockIdx.x & 7) << 6;
  int span = (NN - n0 < 64) ? (NN - n0) : 64;
  int n = n0 + lane;

  for (int c = 0; c < 3; c++){
    const float* base = obs + ((size_t)(b*3 + c)*NN + n0)*TT;
    for (int j = lane; j < span*50; j += 64)
      ol[j/50][c*50 + j%50] = base[j];
  }
  __syncthreads();
  if (n < NN){
    size_t gx = (size_t)(b*NN + n)*XSTRIDE;
    float acc[20];
    #pragma unroll
    for (int o = 0; o < 20; o++) acc[o] = sc2b[o];
    for (int t = 0; t < 48; t++){
      float sv[3];
      #pragma unroll
      for (int co = 0; co < 3; co++) sv[co] = sc1b[co];
      #pragma unroll
      for (int ci = 0; ci < 3; ci++)
        #pragma unroll
        for (int k = 0; k < 3; k++){
          float v = ol[lane][ci*50 + t + k];
          #pragma unroll
          for (int co = 0; co < 3; co++) sv[co] += v * sc1w[co*9 + ci*3 + k];
        }
      #pragma unroll
      for (int co = 0; co < 3; co++){
        float z = lrelu(bnap(sv[co], sbn1, co, 3));
        const float* wp = wT_s2 + (co*48 + t)*20;
        #pragma unroll
        for (int o = 0; o < 20; o++) acc[o] += z * wp[o];
      }
    }
    #pragma unroll
    for (int o = 0; o < 20; o++) xbuf[gx + o] = lrelu(bnap(acc[o], sbn2, o, 20));
    #pragma unroll
    for (int o = 0; o < 20; o++) acc[o] = mc2b[o];
    for (int t = 0; t < 30; t++){
      float mv[3];
      #pragma unroll
      for (int co = 0; co < 3; co++) mv[co] = mc1b[co];
      #pragma unroll
      for (int ci = 0; ci < 3; ci++)
        #pragma unroll
        for (int k = 0; k < 21; k++){
          float v = ol[lane][ci*50 + t + k];
          #pragma unroll
          for (int co = 0; co < 3; co++) mv[co] += v * mc1w[co*63 + ci*21 + k];
        }
      #pragma unroll
      for (int co = 0; co < 3; co++){
        float z = lrelu(bnap(mv[co], mbn1, co, 3));
        const float* wp = wT_m2 + (co*30 + t)*20;
        #pragma unroll
        for (int o = 0; o < 20; o++) acc[o] += z * wp[o];
      }
    }
    #pragma unroll
    for (int o = 0; o < 20; o++) xbuf[gx + 20 + o] = lrelu(bnap(acc[o], mbn2, o, 20));
    #pragma unroll
    for (int c = 0; c < 3; c++){
      float mx = ol[lane][c*50];
      #pragma unroll 7
      for (int t = 1; t < 50; t++) mx = fmaxf(mx, ol[lane][c*50 + t]);
      xbuf[gx + 40 + c] = lrelu(mx);
    }
  }
}

// ============ graph (unchanged from r8) ============
__global__ __launch_bounds__(1024) void k_graph8(
    const float* __restrict__ xbuf, const float* __restrict__ wTg,
    fp gb, fp gbnp, const float* __restrict__ inv_deg,
    const int* __restrict__ begr, const int* __restrict__ e_s,
    float* __restrict__ gbuf)
{
  __shared__ float xin[64][219];
  int tid = threadIdx.x;
  int w = tid >> 6, lane = tid & 63;
  int g0 = blockIdx.x * 64;

  for (int q = 0; q < 4; q++){
    int nl = (w << 2) + q;
    int g = __builtin_amdgcn_readfirstlane(g0 + nl);
    int b = g / NN;
    int n = g - b * NN;
    int gb0 = b * NN;
    float xv = (lane < FF) ? xbuf[(size_t)g*XSTRIDE + lane] : 0.f;
    float ar[4];
    #pragma unroll
    for (int r = 0; r < 4; r++){
      int beg = __builtin_amdgcn_readfirstlane(begr[n*4 + r]);
      int end = __builtin_amdgcn_readfirstlane(begr[n*4 + r + 1]);
      float a = 0.f;
      for (int i = beg; i < end; i++){
        int s = e_s[i];
        a += (lane < FF) ? xbuf[(size_t)(gb0 + s)*XSTRIDE + lane] : 0.f;
      }
      ar[r] = a * inv_deg[r*NN + n];
    }
    if (lane < FF){
      xin[nl][lane]       = xv;
      xin[nl][ 43 + lane] = ar[0];
      xin[nl][ 86 + lane] = ar[1];
      xin[nl][129 + lane] = ar[2];
      xin[nl][172 + lane] = ar[3];
    }
  }
  __syncthreads();

  int c0 = __builtin_amdgcn_readfirstlane(w * 3);
  int g = g0 + lane;
  float acc[3];
  #pragma unroll
  for (int j = 0; j < 3; j++) acc[j] = (c0 + j < FF) ? gb[c0+j] : 0.f;
  for (int f = 0; f < 215; f++){
    float v = xin[lane][f];
    const float* wp = wTg + f*43 + c0;
    #pragma unroll
    for (int j = 0; j < 3; j++) acc[j] += v * wp[j];
  }
  #pragma unroll
  for (int j = 0; j < 3; j++){
    int c = c0 + j;
    if (c < FF)
      gbuf[(size_t)g*XSTRIDE + c] = lrelu(bnap(acc[j], gbnp, c, FF));
  }
}

// ============ head, split into 3 grid-parallel kernels ============
// H1: logits o[b][1+p]; grid (64 b, 8 tiles) x 256
__global__ __launch_bounds__(256) void k_logits9(
    const float* __restrict__ xbuf, const float* __restrict__ gbuf,
    fp action, const int* __restrict__ nts, fp acw, fp acb,
    float* __restrict__ o_ws)
{
  __shared__ float feats[64][87];
  int b = blockIdx.x, tile = blockIdx.y;
  int tid = threadIdx.x;
  int p0 = tile * 64;
  int span = (PP - p0 < 64) ? (PP - p0) : 64;   // 52 on last tile

  for (int j = tid; j < span*86; j += 256){
    int q = j / 86, c = j % 86;
    int np = nts[p0 + q];
    size_t row = (size_t)(b*NN + np)*XSTRIDE;
    feats[q][c] = (c < FF) ? xbuf[row + c] : gbuf[row + (c - FF)];
  }
  __syncthreads();
  if (tid < span){
    int p = p0 + tid;
    float acc = acb[0] + action[b*(PP+1) + 1 + p] * acw[0];
    #pragma unroll 2
    for (int c = 0; c < 86; c++) acc += feats[tid][c] * acw[1 + c];
    o_ws[b*(PP+1) + 1 + p] = acc;
  }
  if (tile == 0 && tid == 64) o_ws[b*(PP+1)] = 0.f;
}

// H2: fc1 partials; grid (64 b, 4 chunks) x 128
__global__ __launch_bounds__(128) void k_fc1_9(
    const float* __restrict__ o_ws, fp aw1, float* __restrict__ part_ws)
{
  __shared__ float os[126];
  int b = blockIdx.x, chunk = blockIdx.y;
  int tid = threadIdx.x;
  int k0 = chunk * 125;
  int kn = (chunk == 3) ? 126 : 125;            // 501 = 125*3 + 126
  if (tid < kn) os[tid] = o_ws[b*(PP+1) + k0 + tid];
  __syncthreads();
  float acc = 0.f;
  for (int k = 0; k < kn; k++) acc += os[k] * aw1[(k0+k)*HH + tid];
  part_ws[(b*4 + chunk)*HH + tid] = acc;
}

// H3: combine -> relu -> fc2 -> fc3 -> softmax; 64 blocks x 512
__global__ __launch_bounds__(512) void k_fc23_9(
    const float* __restrict__ part_ws,
    fp ab1, fp aw2, fp ab2, fp aw3, fp ab3,
    float* __restrict__ out)
{
  int b = blockIdx.x;
  int tid = threadIdx.x;
  __shared__ float h1[HH];
  __shared__ float h2[HH];
  __shared__ float red[512];

  if (tid < HH){
    const float* pw = part_ws + b*4*HH;
    h1[tid] = fmaxf(ab1[tid] + pw[tid] + pw[HH+tid] + pw[2*HH+tid] + pw[3*HH+tid], 0.f);
  }
  __syncthreads();
  if (tid < HH){
    float acc = ab2[tid];
    #pragma unroll 4
    for (int k = 0; k < HH; k++) acc += h1[k] * aw2[k*HH + tid];
    h2[tid] = fmaxf(acc, 0.f);
  }
  __syncthreads();

  float val = -1e30f;
  if (tid <= PP){
    float acc = ab3[tid];
    #pragma unroll 4
    for (int k = 0; k < HH; k++) acc += h2[k] * aw3[k*(PP+1) + tid];
    val = acc;
  }
  red[tid] = val;
  __syncthreads();
  for (int s = 256; s > 0; s >>= 1){
    if (tid < s) red[tid] = fmaxf(red[tid], red[tid + s]);
    __syncthreads();
  }
  float mx = red[0];
  __syncthreads();
  float e = (tid <= PP) ? expf(val - mx) : 0.f;
  red[tid] = e;
  __syncthreads();
  for (int s = 256; s > 0; s >>= 1){
    if (tid < s) red[tid] += red[tid + s];
    __syncthreads();
  }
  float sum = red[0];
  if (tid <= PP) out[b*(PP+1) + tid] = e / sum;
}

extern "C" void kernel_launch(void* const* d_in, const int* in_sizes, int n_in,
                              void* d_out, int out_size, void* d_ws, size_t ws_size,
                              hipStream_t stream)
{
  fp obs    = (fp)d_in[0];
  fp action = (fp)d_in[1];
  const int* ei  = (const int*)d_in[2];
  const int* et  = (const int*)d_in[3];
  const int* nts = (const int*)d_in[4];
  fp sc1w=(fp)d_in[5],  sc1b=(fp)d_in[6],  sbn1=(fp)d_in[7];
  fp sc2w=(fp)d_in[8],  sc2b=(fp)d_in[9],  sbn2=(fp)d_in[10];
  fp mc1w=(fp)d_in[11], mc1b=(fp)d_in[12], mbn1=(fp)d_in[13];
  fp mc2w=(fp)d_in[14], mc2b=(fp)d_in[15], mbn2=(fp)d_in[16];
  fp gwroot=(fp)d_in[17], gwrel=(fp)d_in[18], gb=(fp)d_in[19], gbnp=(fp)d_in[20];
  fp acw=(fp)d_in[21], acb=(fp)d_in[22];
  fp aw1=(fp)d_in[23], ab1=(fp)d_in[24];
  fp aw2=(fp)d_in[25], ab2=(fp)d_in[26];
  fp aw3=(fp)d_in[27], ab3=(fp)d_in[28];

  float* xbuf   = (float*)d_ws;              // 1,536,000
  float* gbuf   = xbuf + 1536000;            // 1,536,000
  float* wT_s2  = gbuf + 1536000;            // 2880
  float* wT_m2  = wT_s2 + 2880;              // 1800
  float* wTg    = wT_m2 + 1800;              // 9312
  float* invdeg = wTg + 9312;                // 2000
  int*   ip     = (int*)(invdeg + 2000);
  int* cnt     = ip;            // 512
  int* ideg    = ip + 512;      // 2048
  int* begr    = ip + 2560;     // 2001
  int* cursor4 = ip + 4561;     // 2000
  int* e_s     = ip + 6561;     // 16000
  float* o_ws    = (float*)(ip + 22561);     // 64*501 = 32064
  float* part_ws = o_ws + 32064;             // 64*4*128 = 32768

  float* out = (float*)d_out;

  hipLaunchKernelGGL(k_prep8, dim3(8), dim3(1024), 0, stream,
    sc2w, mc2w, gwroot, gwrel, wT_s2, wT_m2, wTg, cnt, ideg);
  hipLaunchKernelGGL(k_count8, dim3(63), dim3(256), 0, stream,
    ei, et, cnt, ideg);
  hipLaunchKernelGGL(k_scan8, dim3(1), dim3(512), 0, stream,
    cnt, ideg, begr, cursor4, invdeg);
  hipLaunchKernelGGL(k_fill8, dim3(63), dim3(256), 0, stream,
    ei, et, cursor4, e_s);
  hipLaunchKernelGGL(k_tempo8, dim3(512), dim3(64), 0, stream,
    obs, sc1w, sc1b, sbn1, sc2b, sbn2,
    mc1w, mc1b, mbn1, mc2b, mbn2, wT_s2, wT_m2, xbuf);
  hipLaunchKernelGGL(k_graph8, dim3(500), dim3(1024), 0, stream,
    xbuf, wTg, gb, gbnp, invdeg, begr, e_s, gbuf);
  hipLaunchKernelGGL(k_logits9, dim3(64, 8), dim3(256), 0, stream,
    xbuf, gbuf, action, nts, acw, acb, o_ws);
  hipLaunchKernelGGL(k_fc1_9, dim3(64, 4), dim3(128), 0, stream,
    o_ws, aw1, part_ws);
  hipLaunchKernelGGL(k_fc23_9, dim3(BB), dim3(512), 0, stream,
    part_ws, ab1, aw2, ab2, aw3, ab3, out);
}

// Round 10
// 301.570 us; speedup vs baseline: 1.6015x; 1.0795x over previous
//
#include <hip/hip_runtime.h>

#define SLOPE 0.01f
#define EPSV  1e-5f
#define BB    64
#define NN    500
#define TT    50
#define E_N   16000
#define FF    43
#define PP    500
#define HH    128
#define XSTRIDE 48

typedef const float* fp;

__device__ __forceinline__ float lrelu(float x){ return x >= 0.f ? x : SLOPE * x; }
__device__ __forceinline__ float bnap(float x, fp bnp, int c, int C){
  float g  = bnp[c], b_ = bnp[C + c];
  float m  = bnp[2*C + c], v = bnp[3*C + c];
  float s = g * rsqrtf(v + EPSV);
  return x * s + (b_ - m * s);
}

// ============ prep chain (unchanged from r9) ============
__global__ __launch_bounds__(1024) void k_prep8(
    fp sc2w, fp mc2w, fp gwroot, fp gwrel,
    float* __restrict__ wT_s2, float* __restrict__ wT_m2, float* __restrict__ wTg,
    int* __restrict__ cnt, int* __restrict__ ideg)
{
  int tid = threadIdx.x, blk = blockIdx.x;
  if (blk == 0){
    for (int i = tid; i < 2880; i += 1024){ int o = i/144, x = i%144; wT_s2[x*20+o] = sc2w[i]; }
  } else if (blk == 1){
    for (int i = tid; i < 1800; i += 1024){ int o = i/90,  x = i%90;  wT_m2[x*20+o] = mc2w[i]; }
  } else if (blk < 6){
    for (int i = (blk-2)*1024 + tid; i < 9245; i += 4096){
      int f5 = i/43, g = i%43;
      wTg[i] = (f5 < 43) ? gwroot[f5*43+g] : gwrel[(f5-43)*43+g];
    }
  } else if (blk == 6){
    for (int i = tid; i < 512;  i += 1024) cnt[i] = 0;
    for (int i = tid; i < 2048; i += 1024) ideg[i] = 0;
  } else {
    for (int i = 9245 + tid; i < 9312; i += 1024) wTg[i] = 0.f;
  }
}

__global__ __launch_bounds__(256) void k_count8(
    const int* __restrict__ ei, const int* __restrict__ et,
    int* __restrict__ cnt, int* __restrict__ ideg)
{
  int i = blockIdx.x*256 + threadIdx.x;
  if (i < E_N){
    int d = ei[E_N+i], r = et[i];
    atomicAdd(&cnt[d], 1);
    atomicAdd(&ideg[r*NN+d], 1);
  }
}

__global__ __launch_bounds__(512) void k_scan8(
    const int* __restrict__ cnt, const int* __restrict__ ideg,
    int* __restrict__ begr, int* __restrict__ cursor4, float* __restrict__ inv_deg)
{
  __shared__ int sc[512];
  int tid = threadIdx.x;
  sc[tid] = cnt[tid];
  __syncthreads();
  for (int off = 1; off < 512; off <<= 1){
    int v = (tid >= off) ? sc[tid-off] : 0;
    __syncthreads();
    sc[tid] += v;
    __syncthreads();
  }
  if (tid < NN){
    int o  = tid ? sc[tid-1] : 0;
    int c1 = o  + ideg[tid];
    int c2 = c1 + ideg[NN + tid];
    int c3 = c2 + ideg[2*NN + tid];
    begr[tid*4+0] = o;  begr[tid*4+1] = c1;
    begr[tid*4+2] = c2; begr[tid*4+3] = c3;
    cursor4[tid*4+0] = o;  cursor4[tid*4+1] = c1;
    cursor4[tid*4+2] = c2; cursor4[tid*4+3] = c3;
    #pragma unroll
    for (int r = 0; r < 4; r++)
      inv_deg[r*NN+tid] = 1.f / fmaxf((float)ideg[r*NN+tid], 1.f);
  }
  if (tid == 0) begr[2000] = E_N;
}

__global__ __launch_bounds__(256) void k_fill8(
    const int* __restrict__ ei, const int* __restrict__ et,
    int* __restrict__ cursor4, int* __restrict__ e_s)
{
  int i = blockIdx.x*256 + threadIdx.x;
  if (i < E_N){
    int s = ei[i], d = ei[E_N+i], r = et[i];
    int pos = atomicAdd(&cursor4[d*4+r], 1);
    e_s[pos] = s;
  }
}

// ============ temporal v10: 256-thread blocks, 4 waves split the t-loop ======
// grid 512: b = blk>>3, n0 = (blk&7)*64; lane = node, wave = t-slice.
// Partial conv2 accumulators in LDS; bias+BN+lrelu applied once in reduction.
__global__ __launch_bounds__(256) void k_tempo10(
    fp obs, fp sc1w, fp sc1b, fp sbn1, fp sc2b, fp sbn2,
    fp mc1w, fp mc1b, fp mbn1, fp mc2b, fp mbn2,
    const float* __restrict__ wT_s2, const float* __restrict__ wT_m2,
    float* __restrict__ xbuf)
{
  __shared__ float ol[64][151];       // per-node obs rows (row stride 151: 2-way free)
  __shared__ float pbuf[4][64][21];   // per-wave partials (21: odd stride)
  int tid = threadIdx.x;
  int w = tid >> 6, lane = tid & 63;
  int b  = blockIdx.x >> 3;
  int n0 = (blockIdx.x & 7) << 6;
  int span = (NN - n0 < 64) ? (NN - n0) : 64;

  for (int c = 0; c < 3; c++){
    const float* base = obs + ((size_t)(b*3 + c)*NN + n0)*TT;
    for (int j = tid; j < span*50; j += 256)
      ol[j/50][c*50 + j%50] = base[j];
  }
  __syncthreads();

  size_t gxbase = (size_t)(b*NN + n0)*XSTRIDE;

  // ---- s-branch partials: wave w covers t in [w*12, w*12+12) ----
  {
    float acc[20];
    #pragma unroll
    for (int o = 0; o < 20; o++) acc[o] = 0.f;
    int t0 = w * 12;
    for (int i = 0; i < 12; i++){
      int tt = t0 + i;
      float sv[3];
      #pragma unroll
      for (int co = 0; co < 3; co++) sv[co] = sc1b[co];
      #pragma unroll
      for (int ci = 0; ci < 3; ci++)
        #pragma unroll
        for (int k = 0; k < 3; k++){
          float v = ol[lane][ci*50 + tt + k];
          #pragma unroll
          for (int co = 0; co < 3; co++) sv[co] += v * sc1w[co*9 + ci*3 + k];
        }
      #pragma unroll
      for (int co = 0; co < 3; co++){
        float z = lrelu(bnap(sv[co], sbn1, co, 3));
        const float* wp = wT_s2 + (co*48 + tt)*20;   // uniform -> s_load
        #pragma unroll
        for (int o = 0; o < 20; o++) acc[o] += z * wp[o];
      }
    }
    #pragma unroll
    for (int o = 0; o < 20; o++) pbuf[w][lane][o] = acc[o];
  }
  __syncthreads();
  for (int idx = tid; idx < 64*20; idx += 256){
    int n = idx / 20, o = idx % 20;
    if (n < span){
      float v = pbuf[0][n][o] + pbuf[1][n][o] + pbuf[2][n][o] + pbuf[3][n][o];
      xbuf[gxbase + (size_t)n*XSTRIDE + o] = lrelu(bnap(v + sc2b[o], sbn2, o, 20));
    }
  }
  __syncthreads();

  // ---- m-branch partials: wave w covers t in [w*8, ...); 30 = 8+8+8+6 ----
  {
    int t0 = w * 8;
    int nt = (w == 3) ? 6 : 8;
    float ov[3][28];                   // register segment: window t0..t0+27
    #pragma unroll
    for (int ci = 0; ci < 3; ci++)
      #pragma unroll
      for (int j = 0; j < 28; j++)
        ov[ci][j] = ol[lane][ci*50 + t0 + j];   // overshoot stays in-bounds of LDS alloc
    float acc[20];
    #pragma unroll
    for (int o = 0; o < 20; o++) acc[o] = 0.f;
    #pragma unroll
    for (int i = 0; i < 8; i++){
      if (i < nt){
        int tt = t0 + i;
        float mv[3];
        #pragma unroll
        for (int co = 0; co < 3; co++) mv[co] = mc1b[co];
        #pragma unroll
        for (int ci = 0; ci < 3; ci++)
          #pragma unroll
          for (int k = 0; k < 21; k++){
            float v = ov[ci][i + k];
            #pragma unroll
            for (int co = 0; co < 3; co++) mv[co] += v * mc1w[co*63 + ci*21 + k];
          }
        #pragma unroll
        for (int co = 0; co < 3; co++){
          float z = lrelu(bnap(mv[co], mbn1, co, 3));
          const float* wp = wT_m2 + (co*30 + tt)*20;
          #pragma unroll
          for (int o = 0; o < 20; o++) acc[o] += z * wp[o];
        }
      }
    }
    #pragma unroll
    for (int o = 0; o < 20; o++) pbuf[w][lane][o] = acc[o];
  }
  __syncthreads();
  for (int idx = tid; idx < 64*20; idx += 256){
    int n = idx / 20, o = idx % 20;
    if (n < span){
      float v = pbuf[0][n][o] + pbuf[1][n][o] + pbuf[2][n][o] + pbuf[3][n][o];
      xbuf[gxbase + (size_t)n*XSTRIDE + 20 + o] = lrelu(bnap(v + mc2b[o], mbn2, o, 20));
    }
  }
  __syncthreads();

  // ---- l-branch partials: max over t-slices 13/13/13/11 ----
  {
    int t0 = w * 13;
    int nt = (50 - t0 < 13) ? (50 - t0) : 13;
    float mx[3] = {-1e30f, -1e30f, -1e30f};
    for (int i = 0; i < nt; i++){
      #pragma unroll
      for (int c = 0; c < 3; c++)
        mx[c] = fmaxf(mx[c], ol[lane][c*50 + t0 + i]);
    }
    #pragma unroll
    for (int c = 0; c < 3; c++) pbuf[w][lane][c] = mx[c];
  }
  __syncthreads();
  for (int idx = tid; idx < 64*3; idx += 256){
    int n = idx / 3, c = idx % 3;
    if (n < span){
      float v = fmaxf(fmaxf(pbuf[0][n][c], pbuf[1][n][c]),
                      fmaxf(pbuf[2][n][c], pbuf[3][n][c]));
      xbuf[gxbase + (size_t)n*XSTRIDE + 40 + c] = lrelu(v);
    }
  }
}

// ============ graph (unchanged from r8) ============
__global__ __launch_bounds__(1024) void k_graph8(
    const float* __restrict__ xbuf, const float* __restrict__ wTg,
    fp gb, fp gbnp, const float* __restrict__ inv_deg,
    const int* __restrict__ begr, const int* __restrict__ e_s,
    float* __restrict__ gbuf)
{
  __shared__ float xin[64][219];
  int tid = threadIdx.x;
  int w = tid >> 6, lane = tid & 63;
  int g0 = blockIdx.x * 64;

  for (int q = 0; q < 4; q++){
    int nl = (w << 2) + q;
    int g = __builtin_amdgcn_readfirstlane(g0 + nl);
    int b = g / NN;
    int n = g - b * NN;
    int gb0 = b * NN;
    float xv = (lane < FF) ? xbuf[(size_t)g*XSTRIDE + lane] : 0.f;
    float ar[4];
    #pragma unroll
    for (int r = 0; r < 4; r++){
      int beg = __builtin_amdgcn_readfirstlane(begr[n*4 + r]);
      int end = __builtin_amdgcn_readfirstlane(begr[n*4 + r + 1]);
      float a = 0.f;
      for (int i = beg; i < end; i++){
        int s = e_s[i];
        a += (lane < FF) ? xbuf[(size_t)(gb0 + s)*XSTRIDE + lane] : 0.f;
      }
      ar[r] = a * inv_deg[r*NN + n];
    }
    if (lane < FF){
      xin[nl][lane]       = xv;
      xin[nl][ 43 + lane] = ar[0];
      xin[nl][ 86 + lane] = ar[1];
      xin[nl][129 + lane] = ar[2];
      xin[nl][172 + lane] = ar[3];
    }
  }
  __syncthreads();

  int c0 = __builtin_amdgcn_readfirstlane(w * 3);
  int g = g0 + lane;
  float acc[3];
  #pragma unroll
  for (int j = 0; j < 3; j++) acc[j] = (c0 + j < FF) ? gb[c0+j] : 0.f;
  for (int f = 0; f < 215; f++){
    float v = xin[lane][f];
    const float* wp = wTg + f*43 + c0;
    #pragma unroll
    for (int j = 0; j < 3; j++) acc[j] += v * wp[j];
  }
  #pragma unroll
  for (int j = 0; j < 3; j++){
    int c = c0 + j;
    if (c < FF)
      gbuf[(size_t)g*XSTRIDE + c] = lrelu(bnap(acc[j], gbnp, c, FF));
  }
}

// ============ head (unchanged from r9) ============
__global__ __launch_bounds__(256) void k_logits9(
    const float* __restrict__ xbuf, const float* __restrict__ gbuf,
    fp action, const int* __restrict__ nts, fp acw, fp acb,
    float* __restrict__ o_ws)
{
  __shared__ float feats[64][87];
  int b = blockIdx.x, tile = blockIdx.y;
  int tid = threadIdx.x;
  int p0 = tile * 64;
  int span = (PP - p0 < 64) ? (PP - p0) : 64;

  for (int j = tid; j < span*86; j += 256){
    int q = j / 86, c = j % 86;
    int np = nts[p0 + q];
    size_t row = (size_t)(b*NN + np)*XSTRIDE;
    feats[q][c] = (c < FF) ? xbuf[row + c] : gbuf[row + (c - FF)];
  }
  __syncthreads();
  if (tid < span){
    int p = p0 + tid;
    float acc = acb[0] + action[b*(PP+1) + 1 + p] * acw[0];
    #pragma unroll 2
    for (int c = 0; c < 86; c++) acc += feats[tid][c] * acw[1 + c];
    o_ws[b*(PP+1) + 1 + p] = acc;
  }
  if (tile == 0 && tid == 64) o_ws[b*(PP+1)] = 0.f;
}

__global__ __launch_bounds__(128) void k_fc1_9(
    const float* __restrict__ o_ws, fp aw1, float* __restrict__ part_ws)
{
  __shared__ float os[126];
  int b = blockIdx.x, chunk = blockIdx.y;
  int tid = threadIdx.x;
  int k0 = chunk * 125;
  int kn = (chunk == 3) ? 126 : 125;
  if (tid < kn) os[tid] = o_ws[b*(PP+1) + k0 + tid];
  __syncthreads();
  float acc = 0.f;
  for (int k = 0; k < kn; k++) acc += os[k] * aw1[(k0+k)*HH + tid];
  part_ws[(b*4 + chunk)*HH + tid] = acc;
}

__global__ __launch_bounds__(512) void k_fc23_9(
    const float* __restrict__ part_ws,
    fp ab1, fp aw2, fp ab2, fp aw3, fp ab3,
    float* __restrict__ out)
{
  int b = blockIdx.x;
  int tid = threadIdx.x;
  __shared__ float h1[HH];
  __shared__ float h2[HH];
  __shared__ float red[512];

  if (tid < HH){
    const float* pw = part_ws + b*4*HH;
    h1[tid] = fmaxf(ab1[tid] + pw[tid] + pw[HH+tid] + pw[2*HH+tid] + pw[3*HH+tid], 0.f);
  }
  __syncthreads();
  if (tid < HH){
    float acc = ab2[tid];
    #pragma unroll 4
    for (int k = 0; k < HH; k++) acc += h1[k] * aw2[k*HH + tid];
    h2[tid] = fmaxf(acc, 0.f);
  }
  __syncthreads();

  float val = -1e30f;
  if (tid <= PP){
    float acc = ab3[tid];
    #pragma unroll 4
    for (int k = 0; k < HH; k++) acc += h2[k] * aw3[k*(PP+1) + tid];
    val = acc;
  }
  red[tid] = val;
  __syncthreads();
  for (int s = 256; s > 0; s >>= 1){
    if (tid < s) red[tid] = fmaxf(red[tid], red[tid + s]);
    __syncthreads();
  }
  float mx = red[0];
  __syncthreads();
  float e = (tid <= PP) ? expf(val - mx) : 0.f;
  red[tid] = e;
  __syncthreads();
  for (int s = 256; s > 0; s >>= 1){
    if (tid < s) red[tid] += red[tid + s];
    __syncthreads();
  }
  float sum = red[0];
  if (tid <= PP) out[b*(PP+1) + tid] = e / sum;
}

extern "C" void kernel_launch(void* const* d_in, const int* in_sizes, int n_in,
                              void* d_out, int out_size, void* d_ws, size_t ws_size,
                              hipStream_t stream)
{
  fp obs    = (fp)d_in[0];
  fp action = (fp)d_in[1];
  const int* ei  = (const int*)d_in[2];
  const int* et  = (const int*)d_in[3];
  const int* nts = (const int*)d_in[4];
  fp sc1w=(fp)d_in[5],  sc1b=(fp)d_in[6],  sbn1=(fp)d_in[7];
  fp sc2w=(fp)d_in[8],  sc2b=(fp)d_in[9],  sbn2=(fp)d_in[10];
  fp mc1w=(fp)d_in[11], mc1b=(fp)d_in[12], mbn1=(fp)d_in[13];
  fp mc2w=(fp)d_in[14], mc2b=(fp)d_in[15], mbn2=(fp)d_in[16];
  fp gwroot=(fp)d_in[17], gwrel=(fp)d_in[18], gb=(fp)d_in[19], gbnp=(fp)d_in[20];
  fp acw=(fp)d_in[21], acb=(fp)d_in[22];
  fp aw1=(fp)d_in[23], ab1=(fp)d_in[24];
  fp aw2=(fp)d_in[25], ab2=(fp)d_in[26];
  fp aw3=(fp)d_in[27], ab3=(fp)d_in[28];

  float* xbuf   = (float*)d_ws;              // 1,536,000
  float* gbuf   = xbuf + 1536000;            // 1,536,000
  float* wT_s2  = gbuf + 1536000;            // 2880
  float* wT_m2  = wT_s2 + 2880;              // 1800
  float* wTg    = wT_m2 + 1800;              // 9312
  float* invdeg = wTg + 9312;                // 2000
  int*   ip     = (int*)(invdeg + 2000);
  int* cnt     = ip;            // 512
  int* ideg    = ip + 512;      // 2048
  int* begr    = ip + 2560;     // 2001
  int* cursor4 = ip + 4561;     // 2000
  int* e_s     = ip + 6561;     // 16000
  float* o_ws    = (float*)(ip + 22561);     // 64*501
  float* part_ws = o_ws + 32064;             // 64*4*128

  float* out = (float*)d_out;

  hipLaunchKernelGGL(k_prep8, dim3(8), dim3(1024), 0, stream,
    sc2w, mc2w, gwroot, gwrel, wT_s2, wT_m2, wTg, cnt, ideg);
  hipLaunchKernelGGL(k_count8, dim3(63), dim3(256), 0, stream,
    ei, et, cnt, ideg);
  hipLaunchKernelGGL(k_scan8, dim3(1), dim3(512), 0, stream,
    cnt, ideg, begr, cursor4, invdeg);
  hipLaunchKernelGGL(k_fill8, dim3(63), dim3(256), 0, stream,
    ei, et, cursor4, e_s);
  hipLaunchKernelGGL(k_tempo10, dim3(512), dim3(256), 0, stream,
    obs, sc1w, sc1b, sbn1, sc2b, sbn2,
    mc1w, mc1b, mbn1, mc2b, mbn2, wT_s2, wT_m2, xbuf);
  hipLaunchKernelGGL(k_graph8, dim3(500), dim3(1024), 0, stream,
    xbuf, wTg, gb, gbnp, invdeg, begr, e_s, gbuf);
  hipLaunchKernelGGL(k_logits9, dim3(64, 8), dim3(256), 0, stream,
    xbuf, gbuf, action, nts, acw, acb, o_ws);
  hipLaunchKernelGGL(k_fc1_9, dim3(64, 4), dim3(128), 0, stream,
    o_ws, aw1, part_ws);
  hipLaunchKernelGGL(k_fc23_9, dim3(BB), dim3(512), 0, stream,
    part_ws, ab1, aw2, ab2, aw3, ab3, out);
}